// Round 12
// baseline (100.473 us; speedup 1.0000x reference)
//
#include <hip/hip_runtime.h>
#include <cstdint>
#include <cstddef>

// Problem constants (fixed by setup_inputs)
#define ZSEQ 8
#define NSEQ 2048
#define NH 4
#define DH 128
#define QKV_STRIDE (NH * 3 * DH) /* 1536 floats per token row */
#define OUT_STRIDE (NH * DH)     /* 512 floats per token row */
#define ALPHA 0.08838834764831843f
#define LOG2E 1.4426950408889634f
#define QSCALE (ALPHA * LOG2E)                 /* fold log2e into Q */
#define VSCALE (1.0f / (2048.0f * LOG2E))      /* fold 1/(2048*log2e) into V */
#define TILE_B 16384             /* bytes per 64-row K tile / per V tile */

typedef _Float16 h8 __attribute__((ext_vector_type(8)));
typedef __fp16 fp16x2 __attribute__((ext_vector_type(2)));
typedef float fx16 __attribute__((ext_vector_type(16)));
typedef unsigned int ui4v __attribute__((ext_vector_type(4)));
typedef unsigned short u16t;

__device__ __forceinline__ h8 cvt8(float4 a, float4 b) {
  h8 r;
  r[0] = (_Float16)a.x; r[1] = (_Float16)a.y; r[2] = (_Float16)a.z; r[3] = (_Float16)a.w;
  r[4] = (_Float16)b.x; r[5] = (_Float16)b.y; r[6] = (_Float16)b.z; r[7] = (_Float16)b.w;
  return r;
}

__device__ __forceinline__ unsigned pku(float a, float b) {
  union { fp16x2 h; unsigned u; } c;
  c.h = __builtin_amdgcn_cvt_pkrtz(a, b);
  return c.u;
}

// ---------------------------------------------------------------------------
// Prep: qkv f32 -> FRAGMENT-MAJOR f16 tiles in d_ws (no swizzle; layouts are
// exactly MFMA fragment order so the attn kernel loads them coalesced
// directly from global, no LDS round-trip).
//   Kf[zh][kt][ks=0..7][row=0..63][lh=0..1][8 f16]   (16KB per kv-tile)
//     holds K element-cols 16ks+8lh+e of row n0+row.
//   Vf[zh][kt][ks=0..3][d=0..127][lh=0..1][8 f16]    (16KB per kv-tile)
//     element slot (ks,lh,e) holds V row n0+pi(16ks+8lh+e) at head-dim d,
//     pi = swap bits 2,3 (matches S^T fragment order), VSCALE pre-applied.
// ---------------------------------------------------------------------------
__global__ __launch_bounds__(256) void prep_kernel(const float* __restrict__ qkv,
                                                   const int* __restrict__ seq_offsets,
                                                   char* __restrict__ kf,
                                                   char* __restrict__ vf) {
  __shared__ u16t Vl[64 * 136];  // padded transpose staging
  const int t = threadIdx.x;
  const int b = blockIdx.x;
  const int z = b >> 7;
  const int h = (b >> 5) & 3;
  const int nb = b & 31;
  const int n0 = nb * 64;
  const int start = seq_offsets[z];
  const int zh = z * NH + h;
  const size_t tb = (size_t)(zh * 32 + nb) * TILE_B;

#pragma unroll
  for (int i = 0; i < 2; ++i) {
    const int r = i * 32 + (t >> 3);
    const int ks = t & 7;
    const int c16 = ks * 16;       // element col base of this fragment group
    const float* src = qkv + (size_t)(start + n0 + r) * QKV_STRIDE + h * (3 * DH);
    // ---- K -> fragment-major ----
    float4 a0 = *(const float4*)(src + DH + c16);
    float4 a1 = *(const float4*)(src + DH + c16 + 4);
    float4 a2 = *(const float4*)(src + DH + c16 + 8);
    float4 a3 = *(const float4*)(src + DH + c16 + 12);
    char* kd = kf + tb + ks * 2048 + r * 32;
    *(h8*)(kd) = cvt8(a0, a1);        // lh=0: elems c16..c16+7
    *(h8*)(kd + 16) = cvt8(a2, a3);   // lh=1: elems c16+8..c16+15
    // ---- V -> LDS (row-major, padded), pre-scaled by VSCALE ----
    float4 v0 = *(const float4*)(src + 2 * DH + c16);
    float4 v1 = *(const float4*)(src + 2 * DH + c16 + 4);
    float4 v2 = *(const float4*)(src + 2 * DH + c16 + 8);
    float4 v3 = *(const float4*)(src + 2 * DH + c16 + 12);
    v0.x *= VSCALE; v0.y *= VSCALE; v0.z *= VSCALE; v0.w *= VSCALE;
    v1.x *= VSCALE; v1.y *= VSCALE; v1.z *= VSCALE; v1.w *= VSCALE;
    v2.x *= VSCALE; v2.y *= VSCALE; v2.z *= VSCALE; v2.w *= VSCALE;
    v3.x *= VSCALE; v3.y *= VSCALE; v3.z *= VSCALE; v3.w *= VSCALE;
    *(h8*)((char*)Vl + r * 272 + c16 * 2) = cvt8(v0, v1);
    *(h8*)((char*)Vl + r * 272 + c16 * 2 + 16) = cvt8(v2, v3);
  }
  __syncthreads();
  // transpose out: fragment-major with pi (bits 2,3 of n swapped)
#pragma unroll
  for (int j = 0; j < 2; ++j) {
    const int d = j * 64 + (t >> 2);
    const int ks = t & 3;
    const int n16 = ks * 16;
    h8 o0, o1;
    // lh=0 slot e: V row n16 + pi-order {0,1,2,3,8,9,10,11}
    // lh=1 slot e: V row n16 + 4 + same pattern = {4,5,6,7,12,13,14,15}
#pragma unroll
    for (int k2 = 0; k2 < 8; ++k2) {
      const int r0 = (k2 & 3) + 8 * (k2 >> 2);
      o0[k2] = *(const _Float16*)((const char*)Vl + (n16 + r0) * 272 + d * 2);
      o1[k2] = *(const _Float16*)((const char*)Vl + (n16 + 4 + r0) * 272 + d * 2);
    }
    char* vd = vf + tb + ks * 4096 + d * 32;
    *(h8*)(vd) = o0;        // lh=0
    *(h8*)(vd + 16) = o1;   // lh=1
  }
}

// silu + causal mask on one S^T accumulator (in place).
// s holds s2 = (alpha*log2e) * q.k; silu_ref/2048 = VSCALE * s2*rcp(1+2^-s2),
// with VSCALE folded into V. s element i at n = n0+nbase+(i&3)+8*(i>>2)+4*lh.
__device__ __forceinline__ void silu_mask(fx16& s, int nbase, bool needmask, int n0,
                                          int mrow, int lh) {
#pragma unroll
  for (int i = 0; i < 16; ++i) {
    const float sv = s[i];
    const float e2 = __builtin_amdgcn_exp2f(-sv);
    float sil = sv * __builtin_amdgcn_rcpf(1.0f + e2);
    if (needmask && (n0 + nbase + (i & 3) + 8 * (i >> 2) + 4 * lh > mrow)) sil = 0.0f;
    s[i] = sil;
  }
}

// pack 8 consecutive s elements (b = 0 or 8) into an f16 A-fragment.
__device__ __forceinline__ h8 pack8(const fx16& s, int b) {
  union { ui4v u; h8 h; } cv;
  cv.u = (ui4v){pku(s[b + 0], s[b + 1]), pku(s[b + 2], s[b + 3]),
                pku(s[b + 4], s[b + 5]), pku(s[b + 6], s[b + 7])};
  return cv.h;
}

// ---------------------------------------------------------------------------
// Attention r12 "no-LDS, no-barrier": 1024 blocks = 32 zh x 16 pairs x 2
// halves, 128 threads (2 waves), BM=64 (32 rows/wave). K/V fragments loaded
// DIRECTLY from fragment-major global (fully coalesced); zero LDS, zero
// __syncthreads -> waves never convoy, TLP (2 waves/SIMD, 4 blocks/CU) hides
// all latency. Pair p owns 64-row m-tiles {p, 31-p} (kv spans p+1 and 32-p,
// 33 total); half h2 runs global iters [17*h2, min(33,17*h2+17)). Tile p is
// wholly inside half-0 -> plain store; tile 31-p is split -> both halves
// unsafeAtomicAdd into memset-zeroed out. Math identical to r4..r11.
// ---------------------------------------------------------------------------
__global__ __launch_bounds__(128, 2) void attn_kernel(const float* __restrict__ qkv,
                                                      const int* __restrict__ seq_offsets,
                                                      const char* __restrict__ kf,
                                                      const char* __restrict__ vf,
                                                      float* __restrict__ out) {
  const int t = threadIdx.x;
  const int lane = t & 63;
  const int w = t >> 6;          // 0/1
  const int l31 = lane & 31;
  const int lh = lane >> 5;

  const int bid = blockIdx.x;
  const int zh = bid & 31;       // zh per XCD (bid%8) for K/V L2 locality
  const int p = (bid >> 5) & 15; // pair 0..15
  const int h2 = bid >> 9;       // half 0/1
  const int z = zh >> 2;
  const int h = zh & 3;
  const int start = seq_offsets[z];
  const size_t tbase = (size_t)(zh * 32) * TILE_B;
  const int spanA = p + 1;       // iters for m-tile p (<= 16)
  const int jlo = 17 * h2;
  const int jhi = h2 ? 33 : 17;

  int mt = h2 ? (31 - p) : p;    // 64-row m-tile index
  int wm0 = mt * 64 + w * 32;
  int mrow = wm0 + l31;

  h8 qf[8];
  fx16 oacc[4];

  auto loadQ = [&]() {
    const float* qrow = qkv + (size_t)(start + mrow) * QKV_STRIDE + h * (3 * DH);
#pragma unroll
    for (int ks = 0; ks < 8; ++ks) {
      const int d0 = ks * 16 + lh * 8;
      float4 a = *(const float4*)(qrow + d0);
      float4 b = *(const float4*)(qrow + d0 + 4);
      a.x *= QSCALE; a.y *= QSCALE; a.z *= QSCALE; a.w *= QSCALE;
      b.x *= QSCALE; b.y *= QSCALE; b.z *= QSCALE; b.w *= QSCALE;
      qf[ks] = cvt8(a, b);
    }
  };
  auto zeroAcc = [&]() {
#pragma unroll
    for (int db = 0; db < 4; ++db)
#pragma unroll
      for (int i = 0; i < 16; ++i) oacc[db][i] = 0.0f;
  };
  auto flushStore = [&]() {
#pragma unroll
    for (int db = 0; db < 4; ++db) {
      const int d = db * 32 + l31;
#pragma unroll
      for (int i = 0; i < 16; ++i) {
        const int m = wm0 + (i & 3) + 8 * (i >> 2) + 4 * lh;
        out[(size_t)(start + m) * OUT_STRIDE + h * DH + d] = oacc[db][i];
      }
    }
  };
  auto flushAtomic = [&]() {
#pragma unroll
    for (int db = 0; db < 4; ++db) {
      const int d = db * 32 + l31;
#pragma unroll
      for (int i = 0; i < 16; ++i) {
        const int m = wm0 + (i & 3) + 8 * (i >> 2) + 4 * lh;
        unsafeAtomicAdd(&out[(size_t)(start + m) * OUT_STRIDE + h * DH + d], oacc[db][i]);
      }
    }
  };

  loadQ();
  zeroAcc();

  for (int j = jlo; j < jhi; ++j) {
    if (j == spanA) {  // only reachable in half-0: flush tile p, switch
      flushStore();
      mt = 31 - p;
      wm0 = mt * 64 + w * 32;
      mrow = wm0 + l31;
      loadQ();
      zeroAcc();
    }
    const int kt = (j < spanA) ? j : j - spanA;
    const int n0 = kt * 64;
    const char* kb = kf + tbase + (size_t)kt * TILE_B;
    const char* vb = vf + tbase + (size_t)kt * TILE_B;

    // ---- K fragments straight from global (coalesced 2KB per instr) ----
    h8 a0[8], a1[8];
#pragma unroll
    for (int ks = 0; ks < 8; ++ks) {
      const char* kk = kb + ks * 2048 + l31 * 32 + lh * 16;
      a0[ks] = *(const h8*)(kk);
      a1[ks] = *(const h8*)(kk + 1024);
    }
    // ---- S^T = K Q^T ----
    fx16 s0, s1;
#pragma unroll
    for (int i = 0; i < 16; ++i) { s0[i] = 0.0f; s1[i] = 0.0f; }
    __builtin_amdgcn_s_setprio(1);
#pragma unroll
    for (int ks = 0; ks < 8; ++ks) {
      s0 = __builtin_amdgcn_mfma_f32_32x32x16_f16(a0[ks], qf[ks], s0, 0, 0, 0);
      s1 = __builtin_amdgcn_mfma_f32_32x32x16_f16(a1[ks], qf[ks], s1, 0, 0, 0);
    }
    __builtin_amdgcn_s_setprio(0);

    // ---- V fragments from global; silu VALU hides their latency ----
    h8 bv[4][4];
#pragma unroll
    for (int ks = 0; ks < 4; ++ks) {
#pragma unroll
      for (int db = 0; db < 4; ++db) {
        bv[ks][db] = *(const h8*)(vb + ks * 4096 + (db * 32 + l31) * 32 + lh * 16);
      }
    }
    // ---- silu + mask (in-register), pack to PV A-fragments ----
    const bool needmask = (kt == mt);
    silu_mask(s0, 0, needmask, n0, mrow, lh);
    silu_mask(s1, 32, needmask, n0, mrow, lh);
    h8 pa[4];
    pa[0] = pack8(s0, 0);
    pa[1] = pack8(s0, 8);
    pa[2] = pack8(s1, 0);
    pa[3] = pack8(s1, 8);
    // ---- O += P V ----
    __builtin_amdgcn_s_setprio(1);
#pragma unroll
    for (int ks = 0; ks < 4; ++ks) {
#pragma unroll
      for (int db = 0; db < 4; ++db) {
        oacc[db] = __builtin_amdgcn_mfma_f32_32x32x16_f16(pa[ks], bv[ks][db], oacc[db], 0, 0, 0);
      }
    }
    __builtin_amdgcn_s_setprio(0);
  }
  flushAtomic();  // both halves end in tile 31-p (spanA <= 16 < 17)
}

// ---------------------------------------------------------------------------
// Never-expected fallback (ws too small): naive per-(token,head) block.
// ---------------------------------------------------------------------------
__global__ __launch_bounds__(128) void fallback_kernel(const float* __restrict__ qkv,
                                                       const int* __restrict__ seq_offsets,
                                                       float* __restrict__ out) {
  const int token = blockIdx.x;
  const int h = blockIdx.y;
  const int z = token >> 11;
  const int m = token & 2047;
  const int start = seq_offsets[z];
  const int t = threadIdx.x;  // = d
  const float qd = qkv[(size_t)(start + m) * QKV_STRIDE + h * (3 * DH) + t] * ALPHA;
  __shared__ float red[2];
  float acc = 0.0f;
  for (int n = 0; n <= m; ++n) {
    const float kd = qkv[(size_t)(start + n) * QKV_STRIDE + h * (3 * DH) + DH + t];
    float part = qd * kd;
#pragma unroll
    for (int o = 32; o; o >>= 1) part += __shfl_down(part, o);
    if ((t & 63) == 0) red[t >> 6] = part;
    __syncthreads();
    const float s = red[0] + red[1];
    const float sil = s / ((1.0f + __expf(-s)) * 2048.0f);
    acc += sil * qkv[(size_t)(start + n) * QKV_STRIDE + h * (3 * DH) + 2 * DH + t];
    __syncthreads();
  }
  out[(size_t)(start + m) * OUT_STRIDE + h * DH + t] = acc;
}

// ---------------------------------------------------------------------------
extern "C" void kernel_launch(void* const* d_in, const int* in_sizes, int n_in,
                              void* d_out, int out_size, void* d_ws, size_t ws_size,
                              hipStream_t stream) {
  (void)in_sizes; (void)n_in;
  const float* qkv = (const float*)d_in[0];
  const int* seq_offsets = (const int*)d_in[1];
  // d_in[2..4] (timestamps, ts_weights, pos_weights) unused by the reference.
  float* out = (float*)d_out;

  const size_t half = (size_t)ZSEQ * NH * 32 * TILE_B;  // 16 MiB (bytes)

  if (ws_size >= 2 * half) {
    char* kf = (char*)d_ws;
    char* vf = kf + half;
    hipMemsetAsync(out, 0, (size_t)out_size * sizeof(float), stream);  // atomic targets
    prep_kernel<<<ZSEQ * NH * (NSEQ / 64), 256, 0, stream>>>(qkv, seq_offsets, kf, vf);
    attn_kernel<<<ZSEQ * NH * 16 * 2, 128, 0, stream>>>(qkv, seq_offsets, kf, vf, out);
  } else {
    fallback_kernel<<<dim3(ZSEQ * NSEQ, NH), 128, 0, stream>>>(qkv, seq_offsets, out);
  }
}